// Round 3
// baseline (403.293 us; speedup 1.0000x reference)
//
#include <hip/hip_runtime.h>
#include <stdint.h>

#define TOKENS 32
#define IN_DIM 8192
#define OUT_DIM 8192
#define KSPLIT 8

typedef __bf16 bf16x8 __attribute__((ext_vector_type(8)));
typedef float f32x16 __attribute__((ext_vector_type(16)));

// pack top-16 bits (truncate-to-bf16) of two fp32 into one dword: lo=f0, hi=f1.
// Exact for integer-valued fp32 with |v| <= 255; for A it's round-toward-zero
// (error well inside tolerance).
static __device__ __forceinline__ uint32_t pk_bf16_2(float f0, float f1) {
    return __builtin_amdgcn_perm(__float_as_uint(f1), __float_as_uint(f0), 0x07060302u);
}

// One fused kernel: 32 tokens x 32 outputs per block, K split across 8 waves.
// Weights arrive as int32 (harness sign-extends int8 -> const int*). 256 MB
// streamed once -> HBM-bound. A (32x8192 fp32, 1 MB) is L2-resident; each
// block converts its A slice to bf16 in-register and also accumulates the
// per-token row-sum needed for the zero-point correction:
//   out[t,o] = scale[o] * ( sum_k in[t,k]*q[o,k] - zp[o]*sum_k in[t,k] ) + bias[o]
__global__ __launch_bounds__(512) void gemm_kernel(
        const float* __restrict__ in,
        const int* __restrict__ w,
        const int* __restrict__ zp,
        const float* __restrict__ scale,
        const float* __restrict__ bias,
        float* __restrict__ out) {
    const int tid = threadIdx.x;
    const int wv   = tid >> 6;      // 0..7 : K-split index
    const int lane = tid & 63;
    const int lo   = lane & 31;     // A-row (token) / B-col (output)
    const int hi   = lane >> 5;     // k sub-chunk
    const int obase = blockIdx.x * 32;

    const int KC = IN_DIM / KSPLIT;  // 1024
    const int k0 = wv * KC;

    // A frag: lane -> in[token=lo][k0+ks + hi*8 .. +8]       (fp32, 32 B)
    // B frag: lane -> w [obase+lo][k0+ks + hi*8 .. +8]       (int32, 32 B)
    const float* __restrict__ ap = in + (size_t)lo * IN_DIM + k0 + hi * 8;
    const int*   __restrict__ bp = w  + (size_t)(obase + lo) * IN_DIM + k0 + hi * 8;

    f32x16 acc;
#pragma unroll
    for (int i = 0; i < 16; ++i) acc[i] = 0.f;
    float rs = 0.f;   // partial row-sum of this lane's A elements

#pragma unroll 4
    for (int ks = 0; ks < KC; ks += 16) {
        float4 a0 = *reinterpret_cast<const float4*>(ap + ks);
        float4 a1 = *reinterpret_cast<const float4*>(ap + ks + 4);
        int4   b0 = *reinterpret_cast<const int4*>(bp + ks);
        int4   b1 = *reinterpret_cast<const int4*>(bp + ks + 4);

        rs += (a0.x + a0.y) + (a0.z + a0.w) + (a1.x + a1.y) + (a1.z + a1.w);

        union { uint32_t u[4]; bf16x8 v; } af, bfr;
        af.u[0] = pk_bf16_2(a0.x, a0.y);
        af.u[1] = pk_bf16_2(a0.z, a0.w);
        af.u[2] = pk_bf16_2(a1.x, a1.y);
        af.u[3] = pk_bf16_2(a1.z, a1.w);
        bfr.u[0] = pk_bf16_2((float)b0.x, (float)b0.y);
        bfr.u[1] = pk_bf16_2((float)b0.z, (float)b0.w);
        bfr.u[2] = pk_bf16_2((float)b1.x, (float)b1.y);
        bfr.u[3] = pk_bf16_2((float)b1.z, (float)b1.w);

        acc = __builtin_amdgcn_mfma_f32_32x32x16_bf16(af.v, bfr.v, acc, 0, 0, 0);
    }

    // ---- cross-wave reductions in LDS + fused epilogue ----
    __shared__ float red[KSPLIT][TOKENS * 32];   // 32 KB: K-split partial tiles
    __shared__ float rsl[2 * KSPLIT][32];        // 2 KB : row-sum partials
#pragma unroll
    for (int r = 0; r < 16; ++r) {
        // C/D layout (32x32x16): col = lane&31, row = (r&3) + 8*(r>>2) + 4*hi
        const int m = (r & 3) + 8 * (r >> 2) + 4 * hi;   // token
        red[wv][m * 32 + lo] = acc[r];
    }
    rsl[wv * 2 + hi][lo] = rs;
    __syncthreads();

    for (int i = tid; i < TOKENS * 32; i += 512) {
        float s = 0.f;
#pragma unroll
        for (int wvi = 0; wvi < KSPLIT; ++wvi) s += red[wvi][i];
        const int m = i >> 5;        // token
        const int n = i & 31;        // output within tile
        const int o = obase + n;
        float rsum = 0.f;
#pragma unroll
        for (int j = 0; j < 2 * KSPLIT; ++j) rsum += rsl[j][m];
        out[(size_t)m * OUT_DIM + o] = scale[o] * (s - (float)zp[o] * rsum) + bias[o];
    }
}

extern "C" void kernel_launch(void* const* d_in, const int* in_sizes, int n_in,
                              void* d_out, int out_size, void* d_ws, size_t ws_size,
                              hipStream_t stream) {
    const float* in    = (const float*)d_in[0];
    const int*   wq    = (const int*)d_in[1];   // int8 sign-extended to int32 by harness
    const int*   zp    = (const int*)d_in[2];   // int8 sign-extended to int32
    const float* scale = (const float*)d_in[3];
    const float* bias  = (const float*)d_in[4];
    float* out = (float*)d_out;

    gemm_kernel<<<OUT_DIM / 32, 512, 0, stream>>>(in, wq, zp, scale, bias, out);
}

// Round 5
// 369.034 us; speedup vs baseline: 1.0928x; 1.0928x over previous
//
#include <hip/hip_runtime.h>
#include <stdint.h>

#define TOKENS 32
#define IN_DIM 8192
#define OUT_DIM 8192
#define NWAVE 2                       // K-split waves per block
#define BK 128                        // int32 elements per chunk
#define KRANGE (IN_DIM / NWAVE)       // 4096 k per wave
#define NCHUNK (KRANGE / BK)          // 32 chunks (even)

typedef __bf16 bf16x8 __attribute__((ext_vector_type(8)));
typedef float f32x16 __attribute__((ext_vector_type(16)));

// pack truncate-to-bf16 of two fp32 into one dword (lo=f0, hi=f1).
// Exact for integer-valued fp32 |v|<=255 (the weights); truncation for A.
static __device__ __forceinline__ uint32_t pk_bf16_2(float f0, float f1) {
    return __builtin_amdgcn_perm(__float_as_uint(f1), __float_as_uint(f0), 0x07060302u);
}
static __device__ __forceinline__ float trunc_bf(float f) {
    return __uint_as_float(__float_as_uint(f) & 0xffff0000u);
}

// out[t,o] = scale[o] * ( sum_k A~[t,k]*q[o,k] - zp[o]*sum_k A~[t,k] ) + bias[o]
// A~ = bf16-truncated input (rowsum uses the SAME truncated values -> zp term exact).
// W arrives int32 (harness sign-extends int8 -> const int*): 256 MB streamed once.
__global__ __launch_bounds__(128, 1) void gemm_kernel(
        const float* __restrict__ in,
        const int* __restrict__ w,
        const int* __restrict__ zp,
        const float* __restrict__ scale,
        const float* __restrict__ bias,
        float* __restrict__ out) {
    // per-wave private double buffer: [wave][buf][row][BK] int32 = 64 KB total
    __shared__ int lds[NWAVE][2][32][BK];

    const int tid   = threadIdx.x;
    const int wv    = tid >> 6;       // 0..1 : K-split index
    const int lane  = tid & 63;
    const int lo    = lane & 31;      // A-row (token) / B-row (output)
    const int hi    = lane >> 5;      // k sub-chunk
    const int obase = blockIdx.x * 32;
    const int k0    = wv * KRANGE;

    // Swizzle: LDS[r][d] = W[obase+r][chunk + (d ^ ((r&7)<<2))] (dwords).
    // global_load_lds writes LDS linearly (base + lane*16); the XOR is applied
    // to the per-lane GLOBAL source address (both-sides-or-neither rule).
    const int l5 = lane & 31;
    const int r0 = hi;                                  // lanes>=32 stage odd row of pair

    auto stage = [&](int c, int b) {
#pragma unroll
        for (int p = 0; p < 16; ++p) {
            const int r  = p * 2 + r0;
            const int swr = (r & 7) << 2;
            const int* g = w + (size_t)(obase + r) * IN_DIM + k0 + c * BK
                             + ((l5 * 4) ^ swr);
            __builtin_amdgcn_global_load_lds(
                (const __attribute__((address_space(1))) void*)g,
                (__attribute__((address_space(3))) void*)&lds[wv][b][p * 2][0],
                16, 0, 0);
        }
    };

    const float* ain = in + (size_t)lo * IN_DIM + k0 + hi * 8;
    auto aload = [&](int c, float4 (&ab)[16]) {
#pragma unroll
        for (int j = 0; j < 16; ++j)
            ab[j] = *reinterpret_cast<const float4*>(ain + c * BK + (j >> 1) * 16 + (j & 1) * 4);
    };

    f32x16 acc;
#pragma unroll
    for (int i = 0; i < 16; ++i) acc[i] = 0.f;
    float rs = 0.f;                                     // truncated-A partial rowsum

    const int sw = (lo & 7) << 2;
    const int* lrow0 = &lds[wv][0][lo][0];
    const int* lrow1 = &lds[wv][1][lo][0];

    auto compute = [&](const int* lrow, const float4 (&ab)[16]) {
#pragma unroll
        for (int s = 0; s < 8; ++s) {
            const int d0 = s * 16 + hi * 8;
            const float4 a0 = ab[2 * s];
            const float4 a1 = ab[2 * s + 1];
            int4 b0 = *reinterpret_cast<const int4*>(lrow + (d0 ^ sw));
            int4 b1 = *reinterpret_cast<const int4*>(lrow + ((d0 + 4) ^ sw));

            rs += trunc_bf(a0.x) + trunc_bf(a0.y) + trunc_bf(a0.z) + trunc_bf(a0.w)
                + trunc_bf(a1.x) + trunc_bf(a1.y) + trunc_bf(a1.z) + trunc_bf(a1.w);

            union { uint32_t u[4]; bf16x8 v; } af, bf_;
            af.u[0] = pk_bf16_2(a0.x, a0.y);
            af.u[1] = pk_bf16_2(a0.z, a0.w);
            af.u[2] = pk_bf16_2(a1.x, a1.y);
            af.u[3] = pk_bf16_2(a1.z, a1.w);
            bf_.u[0] = pk_bf16_2((float)b0.x, (float)b0.y);
            bf_.u[1] = pk_bf16_2((float)b0.z, (float)b0.w);
            bf_.u[2] = pk_bf16_2((float)b1.x, (float)b1.y);
            bf_.u[3] = pk_bf16_2((float)b1.z, (float)b1.w);

            acc = __builtin_amdgcn_mfma_f32_32x32x16_bf16(af.v, bf_.v, acc, 0, 0, 0);
        }
    };

    float4 ab0[16], ab1[16];

    // Pipeline: queue order per chunk is [gll_c x16, A_c x16]; vmcnt(32) at the
    // top of compute(c) retires exactly chunk c's 32 ops while leaving chunk
    // c+1's 32 ops (16 KB W + 2 KB A per wave) in flight under the compute.
    stage(0, 0);
    aload(0, ab0);
    for (int cc = 0; cc < NCHUNK; cc += 2) {
        stage(cc + 1, 1);
        aload(cc + 1, ab1);
        asm volatile("s_waitcnt vmcnt(32)" ::: "memory");
        compute(lrow0, ab0);

        if (cc + 2 < NCHUNK) {
            stage(cc + 2, 0);
            aload(cc + 2, ab0);
            asm volatile("s_waitcnt vmcnt(32)" ::: "memory");
        } else {
            asm volatile("s_waitcnt vmcnt(0)" ::: "memory");
        }
        compute(lrow1, ab1);
    }

    // ---- cross-wave reduce (overlay LDS) + fused epilogue ----
    rs += __shfl_down(rs, 32);                          // lanes 0..31: per-token partial
    __syncthreads();                                    // all waves done with bufs
    float* red = (float*)&lds[0][0][0][0];              // [NWAVE][1024]
    float* rsl = red + NWAVE * TOKENS * 32;             // [NWAVE][32]
#pragma unroll
    for (int r = 0; r < 16; ++r) {
        const int m = (r & 3) + 8 * (r >> 2) + 4 * hi;  // token (validated layout)
        red[wv * (TOKENS * 32) + m * 32 + lo] = acc[r];
    }
    if (lane < 32) rsl[wv * 32 + lane] = rs;
    __syncthreads();

    for (int idx = tid; idx < TOKENS * 32; idx += 128) {
        const int m = idx >> 5;
        const int o = obase + (idx & 31);
        float s    = red[idx] + red[TOKENS * 32 + idx];
        float rsum = rsl[m] + rsl[32 + m];
        out[(size_t)m * OUT_DIM + o] = scale[o] * (s - (float)zp[o] * rsum) + bias[o];
    }
}

extern "C" void kernel_launch(void* const* d_in, const int* in_sizes, int n_in,
                              void* d_out, int out_size, void* d_ws, size_t ws_size,
                              hipStream_t stream) {
    const float* in    = (const float*)d_in[0];
    const int*   wq    = (const int*)d_in[1];   // int8 sign-extended to int32 by harness
    const int*   zp    = (const int*)d_in[2];
    const float* scale = (const float*)d_in[3];
    const float* bias  = (const float*)d_in[4];
    float* out = (float*)d_out;

    gemm_kernel<<<OUT_DIM / 32, 128, 0, stream>>>(in, wq, zp, scale, bias, out);
}